// Round 16
// baseline (67.693 us; speedup 1.0000x reference)
//
#include <hip/hip_runtime.h>
#include <hip/hip_bf16.h>
#include <math.h>

#define NN 8192
#define DD 128
#define BIGF 3.402823466e+38f

typedef __attribute__((ext_vector_type(8))) short short8;
typedef __attribute__((ext_vector_type(4))) float f32x4;

static __device__ __forceinline__ unsigned short bfc(float f) {
    return __bfloat16_as_ushort(__float2bfloat16(f));
}

// ---------------- prep: fp32 -> bf16 FRAGMENT-MAJOR + fp32 row norms ----------------
// Fragment-major layout (per 16-row tile rt, per 32-wide k-chunk kk, 1024 B unit):
//   byte = (rt*4 + kk)*1024 + g*256 + c*16 + e*2   with row = rt*16+c, k = kk*32+g*8+e.
// A wave's MFMA fragment load becomes base + lane*16: ONE coalesced 1KB dwordx4.
__global__ __launch_bounds__(256) void prep_kernel(const float* __restrict__ A,
                                                   const float* __restrict__ B,
                                                   char* __restrict__ Af,
                                                   char* __restrict__ Bf,
                                                   float* __restrict__ na,
                                                   float* __restrict__ nb) {
    const float* x = blockIdx.y ? B : A;
    char* xf = blockIdx.y ? Bf : Af;
    float* norm = blockIdx.y ? nb : na;
    const int sub = threadIdx.x >> 5;   // row within block (8 rows/block)
    const int ch  = threadIdx.x & 31;   // float4 chunk: k = ch*4 .. +4
    const int row = blockIdx.x * 8 + sub;
    const float4 v = *(const float4*)(x + (size_t)row * DD + ch * 4);
    float s = v.x * v.x + v.y * v.y + v.z * v.z + v.w * v.w;
    uint2 pk;
    pk.x = ((unsigned)bfc(v.y) << 16) | bfc(v.x);
    pk.y = ((unsigned)bfc(v.w) << 16) | bfc(v.z);
    const int rt = row >> 4, c = row & 15;
    const int kk = ch >> 3, g = (ch >> 1) & 3, e0 = (ch & 1) * 4;
    *(uint2*)(xf + (size_t)(rt * 4 + kk) * 1024 + g * 256 + c * 16 + e0 * 2) = pk;
#pragma unroll
    for (int off = 16; off >= 1; off >>= 1) s += __shfl_xor(s, off, 64);
    if (ch == 0) norm[row] = s;
}

// ---------------- fused MFMA distance pass: NO tile LDS, NO staging barriers ----------------
// loss = 1 - 1/8192 + T/(N*M) - (P_r + P_c)/16384 (hinge never clips: d >= pos).
// Mins on d^2 (sqrt monotone). 128x128 per block, 4 waves (2x2), 64x64/wave.
// Fragments load directly from the fragment-major buffers: coalesced dwordx4
// + 64 MFMA per wave. Fully independent waves until the 2KB epilogue combine.
// Zero atomics (R10); bijective XCD swizzle (R11). (256,2): no VGPR clamp.
// R15 lesson: NO device-scope handshakes anywhere - cross-kernel visibility by
// kernel boundary only (per-XCD L2 non-coherence made the done-counter racy).
__global__ __launch_bounds__(256, 2) void dist_fused(
    const char* __restrict__ Af, const char* __restrict__ Bf,
    const float* __restrict__ na, const float* __restrict__ nb,
    float* __restrict__ rowpart, float* __restrict__ colpart,
    float* __restrict__ totpart) {
    __shared__ float rmbuf[2][128];   // [wc][row_in_block]
    __shared__ float cmbuf[2][128];   // [wr][col_in_block]
    __shared__ float tbuf[4];
    const int tid = threadIdx.x;
    const int l = tid & 63, wid = tid >> 6;
    const int wr = wid >> 1, wc = wid & 1;   // wave 64x64 sub-tile
    const int g = l >> 4, c = l & 15;

    // bijective XCD swizzle (4096 blocks, 8 XCDs)
    const int lin = blockIdx.y * 64 + blockIdx.x;
    const int swz = (lin & 7) * 512 + (lin >> 3);
    const int bx = swz & 63, by = swz >> 6;
    const int rowBase = by * 128;
    const int colBase = bx * 128;

    // fragment bases: row-tile (by*8 + wr*4 + mi), col-tile (bx*8 + wc*4 + ni)
    const char* aF = Af + (size_t)(by * 8 + wr * 4) * 4096 + l * 16;
    const char* bF = Bf + (size_t)(bx * 8 + wc * 4) * 4096 + l * 16;

    f32x4 acc[4][4];
#pragma unroll
    for (int mi = 0; mi < 4; ++mi)
#pragma unroll
        for (int ni = 0; ni < 4; ++ni) acc[mi][ni] = (f32x4)0.f;

#pragma unroll
    for (int kk = 0; kk < 4; ++kk) {
        short8 af[4], bf[4];
#pragma unroll
        for (int mi = 0; mi < 4; ++mi)
            af[mi] = *(const short8*)(aF + mi * 4096 + kk * 1024);
#pragma unroll
        for (int ni = 0; ni < 4; ++ni)
            bf[ni] = *(const short8*)(bF + ni * 4096 + kk * 1024);
#pragma unroll
        for (int mi = 0; mi < 4; ++mi)
#pragma unroll
            for (int ni = 0; ni < 4; ++ni)
                acc[mi][ni] = __builtin_amdgcn_mfma_f32_16x16x32_bf16(
                    af[mi], bf[ni], acc[mi][ni], 0, 0, 0);
    }

    // out_row = row0 + mi*16 + g*4 + reg ; out_col = col0 + ni*16 + c
    const int row0 = rowBase + wr * 64;
    const int col0 = colBase + wc * 64;

    float nbc[4];
#pragma unroll
    for (int ni = 0; ni < 4; ++ni) nbc[ni] = nb[col0 + ni * 16 + c];

    float colm2[4] = {BIGF, BIGF, BIGF, BIGF};
    f32x4 tot4 = (f32x4)0.f;
#pragma unroll
    for (int mi = 0; mi < 4; ++mi) {
        const f32x4 na4 = *(const f32x4*)(na + row0 + mi * 16 + g * 4);
        float rowm2[4] = {BIGF, BIGF, BIGF, BIGF};
#pragma unroll
        for (int ni = 0; ni < 4; ++ni) {
            f32x4 a = acc[mi][ni];
#pragma unroll
            for (int reg = 0; reg < 4; ++reg) {
                float d2 = fmaf(-2.0f, a[reg], na4[reg] + nbc[ni]);
                rowm2[reg] = fminf(rowm2[reg], d2);
                colm2[ni] = fminf(colm2[ni], d2);
                tot4[reg] += __builtin_amdgcn_sqrtf(fmaxf(d2, 0.f));
            }
        }
#pragma unroll
        for (int reg = 0; reg < 4; ++reg) {
            float m = rowm2[reg];
            m = fminf(m, __shfl_xor(m, 1, 64));
            m = fminf(m, __shfl_xor(m, 2, 64));
            m = fminf(m, __shfl_xor(m, 4, 64));
            m = fminf(m, __shfl_xor(m, 8, 64));
            if (c == 0) rmbuf[wc][wr * 64 + mi * 16 + g * 4 + reg] = m;
        }
    }
#pragma unroll
    for (int ni = 0; ni < 4; ++ni) {
        float m = colm2[ni];
        m = fminf(m, __shfl_xor(m, 16, 64));
        m = fminf(m, __shfl_xor(m, 32, 64));
        if (g == 0) cmbuf[wr][wc * 64 + ni * 16 + c] = m;
    }
    float tot = (tot4[0] + tot4[1]) + (tot4[2] + tot4[3]);
#pragma unroll
    for (int off = 32; off >= 1; off >>= 1) tot += __shfl_xor(tot, off, 64);
    if (l == 0) tbuf[wid] = tot;
    __syncthreads();

    // plain disjoint stores - no atomics anywhere
    if (tid < 128) {
        rowpart[(size_t)bx * NN + rowBase + tid] = fminf(rmbuf[0][tid], rmbuf[1][tid]);
    } else if (tid < 256) {
        int j = tid - 128;
        colpart[(size_t)by * NN + colBase + j] = fminf(cmbuf[0][j], cmbuf[1][j]);
    }
    if (tid == 0)
        totpart[by * 64 + bx] = tbuf[0] + tbuf[1] + tbuf[2] + tbuf[3];
}

// ---------------- fin1: 64-way partial reduce (64 blocks x 256 threads) ----------------
__global__ __launch_bounds__(256) void fin1_kernel(const float* __restrict__ rowpart,
                                                   const float* __restrict__ colpart,
                                                   const float* __restrict__ totpart,
                                                   float* __restrict__ finpart) {
    const int idx = blockIdx.x * 256 + threadIdx.x;   // 0..16383
    const int j = (idx < NN) ? idx : idx - NN;
    const float* p = (idx < NN) ? rowpart : colpart;
    float m = BIGF;
#pragma unroll 8
    for (int k = 0; k < 64; ++k) m = fminf(m, p[(size_t)k * NN + j]);
    float contrib = -__builtin_amdgcn_sqrtf(fmaxf(m, 0.f)) * (1.0f / 16384.0f);
    if (blockIdx.x < 16)
        contrib += totpart[blockIdx.x * 256 + threadIdx.x] * (1.0f / 67108864.0f);
#pragma unroll
    for (int off = 32; off >= 1; off >>= 1) contrib += __shfl_xor(contrib, off, 64);
    __shared__ float red[4];
    if ((threadIdx.x & 63) == 0) red[threadIdx.x >> 6] = contrib;
    __syncthreads();
    if (threadIdx.x == 0)
        finpart[blockIdx.x] = red[0] + red[1] + red[2] + red[3];
}

// ---------------- fin2: final scalar (race-free: kernel-boundary visibility) ----------------
__global__ __launch_bounds__(64) void fin2_kernel(const float* __restrict__ finpart,
                                                  float* __restrict__ out) {
    float s = finpart[threadIdx.x];
#pragma unroll
    for (int off = 32; off >= 1; off >>= 1) s += __shfl_xor(s, off, 64);
    if (threadIdx.x == 0) out[0] = s + 1.0f - 1.0f / 8192.0f;
}

extern "C" void kernel_launch(void* const* d_in, const int* in_sizes, int n_in,
                              void* d_out, int out_size, void* d_ws, size_t ws_size,
                              hipStream_t stream) {
    const float* A = (const float*)d_in[0];
    const float* B = (const float*)d_in[1];
    char* ws = (char*)d_ws;

    const size_t MB = 1024 * 1024;
    char* Af       = ws;                                          // 2 MB frag-major
    char* Bf       = ws + 2 * MB;                                 // 2 MB frag-major
    float* na      = (float*)(ws + 4 * MB);                       // 32 KB
    float* nb      = (float*)(ws + 4 * MB + 32768);               // 32 KB
    float* rowpart = (float*)(ws + 4 * MB + 65536);               // 2 MB  [ct][8192]
    float* colpart = (float*)(ws + 6 * MB + 65536);               // 2 MB  [rt][8192]
    float* totpart = (float*)(ws + 8 * MB + 65536);               // 16 KB
    float* finpart = (float*)(ws + 8 * MB + 65536 + 16384);       // 256 B

    dim3 pgrid(NN / 8, 2);
    prep_kernel<<<pgrid, 256, 0, stream>>>(A, B, Af, Bf, na, nb);

    dim3 grid(NN / 128, NN / 128);
    dist_fused<<<grid, 256, 0, stream>>>(Af, Bf, na, nb, rowpart, colpart, totpart);

    fin1_kernel<<<64, 256, 0, stream>>>(rowpart, colpart, totpart, finpart);
    fin2_kernel<<<1, 64, 0, stream>>>(finpart, (float*)d_out);
}